// Round 5
// baseline (156.325 us; speedup 1.0000x reference)
//
#include <hip/hip_runtime.h>

// CalcSpixelFeats R24. Base = R23 (151.5us total; mfma kernel 73.5us).
// R23 post-mortem: all pipes idle (Mfma 3%, VALU 5%, HBM 9%, occ 17.7%);
// static model says ~12us -> the cost is (a) __syncthreads draining vmcnt(0)
// 3x per chunk in lockstep at 2 blocks/CU, (b) 27.6 MB end-of-kernel atomic
// RMW burst onto 2112 lines (WRITE_SIZE matched the model exactly).
// R24, same GEMM core:
//  1) raw barriers: s_waitcnt lgkmcnt(0) + s_barrier -> global loads survive
//     barriers (LDS visibility is all we need; loads land in registers).
//  2) register prefetch of chunk n+1 loads during chunk n scatter phase.
//  3) 1024 blocks x 4 chunks -> 4 blocks/CU (LDS 38.9KB*4 = 155.6 <= 160KB).
//  4) flush = plain per-block partial stores (no atomics, no memset);
//     finalize kernel does the cross-block reduction + division. 2 dispatches.

#define CCH  32
#define KMAX 256
#define FST  (CCH + 1)       // 33
#define KFS  (KMAX * FST)    // 8448 floats per block-partial

typedef __attribute__((ext_vector_type(4))) int   int4v;
typedef __attribute__((ext_vector_type(4))) float f32x4;

__device__ __forceinline__ unsigned pack_bf16(float a, float b) {
    unsigned ua = __float_as_uint(a);
    unsigned ub = __float_as_uint(b);
    ua = (ua + 0x7FFFu + ((ua >> 16) & 1u)) >> 16;   // RNE
    ub = (ub + 0x7FFFu + ((ub >> 16) & 1u)) >> 16;
    return ua | (ub << 16);
}
__device__ __forceinline__ unsigned short bf16_1(float a) {
    unsigned ua = __float_as_uint(a);
    return (unsigned short)((ua + 0x7FFFu + ((ua >> 16) & 1u)) >> 16);
}

__device__ __forceinline__ void wg_barrier() {
    // LDS-visibility barrier WITHOUT the __syncthreads vmcnt(0) drain:
    // prefetched global loads (register destinations) stay in flight.
    asm volatile("s_waitcnt lgkmcnt(0)" ::: "memory");
    __builtin_amdgcn_s_barrier();
}

// A slot for A[t][p] (t bin 0..255, p px 0..63): region=(t>>4)*2+(p>>5),
// q=p&31, lane=(t&15)+16*(q>>3), elem=q&7. B slot for B[p][c]:
// region=(c>>4)*2+(p>>5), lane=(c&15)+16*(q>>3), elem=q&7.

__global__ __launch_bounds__(256, 4) void spx_mfma_kernel(
    const float* __restrict__ pf,      // [B][C][P]
    const float* __restrict__ assoc,   // [B][9][P]
    const int*   __restrict__ idxmap,  // [B][P]
    const int*   __restrict__ nw_p,
    const int*   __restrict__ nh_p,
    float*       __restrict__ part,    // [B*bpbk][KFS] block partials
    int P, int K, int cpb, int bpbk)   // chunks/block, blocks/batch
{
    __shared__ __align__(16) short lsA[16 * 2 * 64 * 8];  // 32 KB
    __shared__ __align__(16) short lsB[6 * 64 * 8];       // 6 KB

    const int tid  = threadIdx.x;
    const int wave = tid >> 6;
    const int lane = tid & 63;
    const int b    = blockIdx.x / bpbk;
    const int blkb = blockIdx.x - b * bpbk;

    const int nw = nw_p[0], nh = nh_p[0];

    // static ones-region ct=2 (regions 4,5): B[p][32]=1, B[p][33..47]=0
    if (tid < 128) {
        const int reg = 4 + (tid >> 6);
        const int ln  = tid & 63;
        uint4 v = ((ln & 15) == 0)
            ? make_uint4(0x3F803F80u, 0x3F803F80u, 0x3F803F80u, 0x3F803F80u)
            : make_uint4(0u, 0u, 0u, 0u);
        *(uint4*)&lsB[(reg * 64 + ln) * 8] = v;
    }

    const int*   ix_b = idxmap + (size_t)b * P;
    const float* pf_b = pf     + (size_t)b * CCH * P;
    const float* as_b = assoc  + (size_t)b * 9 * P;

    f32x4 acc[4][3];
#pragma unroll
    for (int i = 0; i < 4; ++i)
#pragma unroll
        for (int j = 0; j < 3; ++j) acc[i][j] = f32x4{0.f, 0.f, 0.f, 0.f};

    const int grp = tid >> 6;   // j-group for scatter
    const int pl  = tid & 63;   // scatter pixel
    const int pp  = tid & 31;   // pixel-pair index for F staging
    const int cg  = tid >> 5;   // channel group 0..7

    // ---- prefetch chunk 0 into registers ----
    int    idxR;
    float  wvR[3];
    float2 fvR[4];
    {
        const int p0 = (blkb * cpb) * 64;
        idxR = ix_b[p0 + pl];
#pragma unroll
        for (int wi = 0; wi < 3; ++wi) {
            const int j = grp + 4 * wi;
            wvR[wi] = (j < 9) ? as_b[(size_t)j * P + p0 + pl] : 0.f;
        }
#pragma unroll
        for (int ci = 0; ci < 4; ++ci) {
            const int c = cg + 8 * ci;
            fvR[ci] = *(const float2*)&pf_b[(size_t)c * P + p0 + 2 * pp];
        }
    }

    for (int ch = 0; ch < cpb; ++ch) {
        // Phase Z: zero the A-fragment table (8 x uint4 per thread = 32 KB)
#pragma unroll
        for (int i = 0; i < 8; ++i)
            *(uint4*)&lsA[(tid + 256 * i) * 8] = make_uint4(0u, 0u, 0u, 0u);

        wg_barrier();   // zeroing visible

        // Phase S: consume prefetched regs
        const int   idx = idxR;
        float       wv0 = wvR[0], wv1 = wvR[1], wv2 = wvR[2];
        const float2 fv0 = fvR[0], fv1 = fvR[1], fv2 = fvR[2], fv3 = fvR[3];

        // scatter A: bf16(w) -> slot (tbin, pl); 9 distinct bins/pixel ->
        // collision-free plain ds_write_b16, no atomics
        const int iy  = idx / nw;
        const int ixx = idx - iy * nw;
        const int q   = pl & 31;
        const int ps_ = pl >> 5;
        const float wvv[3] = {wv0, wv1, wv2};
#pragma unroll
        for (int wi = 0; wi < 3; ++wi) {
            const int j = grp + 4 * wi;
            if (j >= 9) continue;
            const int ty = iy + j / 3 - 1;
            const int tx = ixx + j % 3 - 1;
            if (tx < 0 || tx >= nw || ty < 0 || ty >= nh) continue;
            const int t   = ty * nw + tx;
            const int off = ((((t >> 4) * 2 + ps_) * 64
                              + (t & 15) + ((q >> 3) << 4)) * 8) + (q & 7);
            lsA[off] = (short)bf16_1(wvv[wi]);
        }

        // stage B: feature pairs (k=p contiguous per lane -> b32 writes)
        {
            const float2 fvv[4] = {fv0, fv1, fv2, fv3};
#pragma unroll
            for (int ci = 0; ci < 4; ++ci) {
                const int c  = cg + 8 * ci;
                const int p2 = 2 * pp;
                const int q2 = p2 & 31;
                const int off = ((((c >> 4) * 2 + (p2 >> 5)) * 64
                                  + (c & 15) + ((q2 >> 3) << 4)) * 8) + (q2 & 7);
                *(unsigned*)&lsB[off] = pack_bf16(fvv[ci].x, fvv[ci].y);
            }
        }

        // issue prefetch for chunk ch+1 (stays in flight across barriers)
        {
            const int chn = (ch + 1 < cpb) ? ch + 1 : ch;
            const int p0n = (blkb * cpb + chn) * 64;
            idxR = ix_b[p0n + pl];
#pragma unroll
            for (int wi = 0; wi < 3; ++wi) {
                const int j = grp + 4 * wi;
                wvR[wi] = (j < 9) ? as_b[(size_t)j * P + p0n + pl] : 0.f;
            }
#pragma unroll
            for (int ci = 0; ci < 4; ++ci) {
                const int c = cg + 8 * ci;
                fvR[ci] = *(const float2*)&pf_b[(size_t)c * P + p0n + 2 * pp];
            }
        }

        wg_barrier();   // fragments staged

        // Phase M: wave owns k-tiles 4w..4w+3; 3 c-tiles; 2 p-subtiles
#pragma unroll
        for (int ps = 0; ps < 2; ++ps) {
            int4v bfr[3];
#pragma unroll
            for (int ct = 0; ct < 3; ++ct)
                bfr[ct] = *(int4v*)&lsB[((ct * 2 + ps) * 64 + lane) * 8];
#pragma unroll
            for (int ktl = 0; ktl < 4; ++ktl) {
                const int kt = wave * 4 + ktl;
                int4v af = *(int4v*)&lsA[((kt * 2 + ps) * 64 + lane) * 8];
#pragma unroll
                for (int ct = 0; ct < 3; ++ct) {
                    asm("v_mfma_f32_16x16x32_bf16 %0, %1, %2, %0"
                        : "+v"(acc[ktl][ct])
                        : "v"(af), "v"(bfr[ct]));
                }
            }
        }

        wg_barrier();   // frags consumed; next Phase Z may overwrite
    }

    // MFMA -> VALU read hazard guard before the flush reads acc
    asm volatile("s_nop 7\n\ts_nop 7");

    // flush: plain streaming stores of this block's partial (no atomics)
    float* pb = part + (size_t)(b * bpbk + blkb) * KFS;
    const int col = lane & 15;
    const int rw0 = (lane >> 4) * 4;
#pragma unroll
    for (int ktl = 0; ktl < 4; ++ktl) {
        const int kt = wave * 4 + ktl;
#pragma unroll
        for (int ct = 0; ct < 3; ++ct) {
            const int c = ct * 16 + col;
            if (c > CCH) continue;      // ct=2: only col 0 (wsum) is real
#pragma unroll
            for (int i = 0; i < 4; ++i) {
                const int k = kt * 16 + rw0 + i;
                pb[(size_t)k * FST + c] = acc[ktl][ct][i];
            }
        }
    }
}

// Finalize: block per (batch, 4-bin group). Phase 1: threads 0..131 reduce
// the 132 partial columns across bpbk blocks (coalesced stride-KFS reads).
// Phase 2: threads 0..127 divide and write out[b][c][k].
__global__ __launch_bounds__(192) void spx_finalize_kernel(
    const float* __restrict__ part,   // [B*bpbk][KFS]
    float*       __restrict__ out,    // [B][C][K]
    int K, int bpbk)
{
    __shared__ float red[4 * FST];    // 132 floats

    const int gpb = KMAX / 4;         // 64 groups per batch
    const int b   = blockIdx.x / gpb;
    const int g   = blockIdx.x - b * gpb;
    const int tid = threadIdx.x;

    if (tid < 4 * FST) {
        const float* p = part + (size_t)b * bpbk * KFS + g * 4 * FST + tid;
        float s = 0.f;
        for (int blk = 0; blk < bpbk; ++blk) s += p[(size_t)blk * KFS];
        red[tid] = s;
    }
    __syncthreads();

    if (tid < 128) {
        const int kl = tid >> 5;      // 0..3
        const int c  = tid & 31;
        const float W = red[kl * FST + CCH];
        const float v = red[kl * FST + c];
        out[((size_t)b * CCH + c) * K + (g * 4 + kl)] =
            (W > 1e-16f) ? v / W : 0.f;
    }
}

extern "C" void kernel_launch(void* const* d_in, const int* in_sizes, int n_in,
                              void* d_out, int out_size, void* d_ws, size_t ws_size,
                              hipStream_t stream) {
    const float* pf     = (const float*)d_in[0];
    const float* assoc  = (const float*)d_in[1];
    const int*   idxmap = (const int*)d_in[2];
    const int*   nw_p   = (const int*)d_in[3];
    const int*   nh_p   = (const int*)d_in[4];
    float* out = (float*)d_out;

    const int BP = in_sizes[2];          // B*P = 262144
    const int B  = 4;                    // fixed by reference setup
    const int P  = BP / B;               // 65536
    const int K  = out_size / (B * CCH); // 256 (== KMAX)

    // partials are the only workspace user; pick bpbk to fit
    int bpbk = 256;                      // 1024 blocks -> 4 blocks/CU
    while ((size_t)B * bpbk * KFS * sizeof(float) > ws_size && bpbk > 64)
        bpbk >>= 1;
    const int cpb = (P / 64) / bpbk;     // 4 (or 8/16 fallback)
    float* part = (float*)d_ws;

    spx_mfma_kernel<<<B * bpbk, 256, 0, stream>>>(
        pf, assoc, idxmap, nw_p, nh_p, part, P, K, cpb, bpbk);

    spx_finalize_kernel<<<B * (KMAX / 4), 192, 0, stream>>>(
        part, out, K, bpbk);
}

// Round 7
// 104.245 us; speedup vs baseline: 1.4996x; 1.4996x over previous
//
#include <hip/hip_runtime.h>

// CalcSpixelFeats R26 == R25 resubmitted verbatim (R25 bench was a
// GPUAcquisitionTimeout — infra failure, no measurement; theory untested).
// Base = R24 (156.3us; finalize 65.2us, mfma ~20us).
// R24 post-mortem: finalize was latency-bound by construction — 132 active
// threads/block doing a 256-deep SERIAL walk at 33KB stride (256 x ~600cy
// = 64us, matches), 1 block/CU, 325 GB/s. The mfma kernel's raw-barrier +
// prefetch + 4-blocks/CU changes worked (dropped out of top-5, ~20us).
// R25/R26: mfma kernel UNCHANGED. Reduction restructured for parallelism+MLP:
//  Stage A: 528 blocks (B x 132), 256 thr; block owns 64 consecutive columns;
//    wave w lane l sums col g*64+l over blk=w+4i -> 256B coalesced wave-loads,
//    4 independent accumulators, LDS cross-wave combine, coalesced fsum store.
//  Stage B: trivial division kernel (fsum 135KB, L2-hot).

#define CCH  32
#define KMAX 256
#define FST  (CCH + 1)       // 33
#define KFS  (KMAX * FST)    // 8448 floats per block-partial

typedef __attribute__((ext_vector_type(4))) int   int4v;
typedef __attribute__((ext_vector_type(4))) float f32x4;

__device__ __forceinline__ unsigned pack_bf16(float a, float b) {
    unsigned ua = __float_as_uint(a);
    unsigned ub = __float_as_uint(b);
    ua = (ua + 0x7FFFu + ((ua >> 16) & 1u)) >> 16;   // RNE
    ub = (ub + 0x7FFFu + ((ub >> 16) & 1u)) >> 16;
    return ua | (ub << 16);
}
__device__ __forceinline__ unsigned short bf16_1(float a) {
    unsigned ua = __float_as_uint(a);
    return (unsigned short)((ua + 0x7FFFu + ((ua >> 16) & 1u)) >> 16);
}

__device__ __forceinline__ void wg_barrier() {
    // LDS-visibility barrier WITHOUT the __syncthreads vmcnt(0) drain:
    // prefetched global loads (register destinations) stay in flight.
    asm volatile("s_waitcnt lgkmcnt(0)" ::: "memory");
    __builtin_amdgcn_s_barrier();
}

// A slot for A[t][p] (t bin 0..255, p px 0..63): region=(t>>4)*2+(p>>5),
// q=p&31, lane=(t&15)+16*(q>>3), elem=q&7. B slot for B[p][c]:
// region=(c>>4)*2+(p>>5), lane=(c&15)+16*(q>>3), elem=q&7.

__global__ __launch_bounds__(256, 4) void spx_mfma_kernel(
    const float* __restrict__ pf,      // [B][C][P]
    const float* __restrict__ assoc,   // [B][9][P]
    const int*   __restrict__ idxmap,  // [B][P]
    const int*   __restrict__ nw_p,
    const int*   __restrict__ nh_p,
    float*       __restrict__ part,    // [B*bpbk][KFS] block partials
    int P, int K, int cpb, int bpbk)   // chunks/block, blocks/batch
{
    __shared__ __align__(16) short lsA[16 * 2 * 64 * 8];  // 32 KB
    __shared__ __align__(16) short lsB[6 * 64 * 8];       // 6 KB

    const int tid  = threadIdx.x;
    const int wave = tid >> 6;
    const int lane = tid & 63;
    const int b    = blockIdx.x / bpbk;
    const int blkb = blockIdx.x - b * bpbk;

    const int nw = nw_p[0], nh = nh_p[0];

    // static ones-region ct=2 (regions 4,5): B[p][32]=1, B[p][33..47]=0
    if (tid < 128) {
        const int reg = 4 + (tid >> 6);
        const int ln  = tid & 63;
        uint4 v = ((ln & 15) == 0)
            ? make_uint4(0x3F803F80u, 0x3F803F80u, 0x3F803F80u, 0x3F803F80u)
            : make_uint4(0u, 0u, 0u, 0u);
        *(uint4*)&lsB[(reg * 64 + ln) * 8] = v;
    }

    const int*   ix_b = idxmap + (size_t)b * P;
    const float* pf_b = pf     + (size_t)b * CCH * P;
    const float* as_b = assoc  + (size_t)b * 9 * P;

    f32x4 acc[4][3];
#pragma unroll
    for (int i = 0; i < 4; ++i)
#pragma unroll
        for (int j = 0; j < 3; ++j) acc[i][j] = f32x4{0.f, 0.f, 0.f, 0.f};

    const int grp = tid >> 6;   // j-group for scatter
    const int pl  = tid & 63;   // scatter pixel
    const int pp  = tid & 31;   // pixel-pair index for F staging
    const int cg  = tid >> 5;   // channel group 0..7

    // ---- prefetch chunk 0 into registers ----
    int    idxR;
    float  wvR[3];
    float2 fvR[4];
    {
        const int p0 = (blkb * cpb) * 64;
        idxR = ix_b[p0 + pl];
#pragma unroll
        for (int wi = 0; wi < 3; ++wi) {
            const int j = grp + 4 * wi;
            wvR[wi] = (j < 9) ? as_b[(size_t)j * P + p0 + pl] : 0.f;
        }
#pragma unroll
        for (int ci = 0; ci < 4; ++ci) {
            const int c = cg + 8 * ci;
            fvR[ci] = *(const float2*)&pf_b[(size_t)c * P + p0 + 2 * pp];
        }
    }

    for (int ch = 0; ch < cpb; ++ch) {
        // Phase Z: zero the A-fragment table (8 x uint4 per thread = 32 KB)
#pragma unroll
        for (int i = 0; i < 8; ++i)
            *(uint4*)&lsA[(tid + 256 * i) * 8] = make_uint4(0u, 0u, 0u, 0u);

        wg_barrier();   // zeroing visible

        // Phase S: consume prefetched regs
        const int   idx = idxR;
        float       wv0 = wvR[0], wv1 = wvR[1], wv2 = wvR[2];
        const float2 fv0 = fvR[0], fv1 = fvR[1], fv2 = fvR[2], fv3 = fvR[3];

        // scatter A: bf16(w) -> slot (tbin, pl); 9 distinct bins/pixel ->
        // collision-free plain ds_write_b16, no atomics
        const int iy  = idx / nw;
        const int ixx = idx - iy * nw;
        const int q   = pl & 31;
        const int ps_ = pl >> 5;
        const float wvv[3] = {wv0, wv1, wv2};
#pragma unroll
        for (int wi = 0; wi < 3; ++wi) {
            const int j = grp + 4 * wi;
            if (j >= 9) continue;
            const int ty = iy + j / 3 - 1;
            const int tx = ixx + j % 3 - 1;
            if (tx < 0 || tx >= nw || ty < 0 || ty >= nh) continue;
            const int t   = ty * nw + tx;
            const int off = ((((t >> 4) * 2 + ps_) * 64
                              + (t & 15) + ((q >> 3) << 4)) * 8) + (q & 7);
            lsA[off] = (short)bf16_1(wvv[wi]);
        }

        // stage B: feature pairs (k=p contiguous per lane -> b32 writes)
        {
            const float2 fvv[4] = {fv0, fv1, fv2, fv3};
#pragma unroll
            for (int ci = 0; ci < 4; ++ci) {
                const int c  = cg + 8 * ci;
                const int p2 = 2 * pp;
                const int q2 = p2 & 31;
                const int off = ((((c >> 4) * 2 + (p2 >> 5)) * 64
                                  + (c & 15) + ((q2 >> 3) << 4)) * 8) + (q2 & 7);
                *(unsigned*)&lsB[off] = pack_bf16(fvv[ci].x, fvv[ci].y);
            }
        }

        // issue prefetch for chunk ch+1 (stays in flight across barriers)
        {
            const int chn = (ch + 1 < cpb) ? ch + 1 : ch;
            const int p0n = (blkb * cpb + chn) * 64;
            idxR = ix_b[p0n + pl];
#pragma unroll
            for (int wi = 0; wi < 3; ++wi) {
                const int j = grp + 4 * wi;
                wvR[wi] = (j < 9) ? as_b[(size_t)j * P + p0n + pl] : 0.f;
            }
#pragma unroll
            for (int ci = 0; ci < 4; ++ci) {
                const int c = cg + 8 * ci;
                fvR[ci] = *(const float2*)&pf_b[(size_t)c * P + p0n + 2 * pp];
            }
        }

        wg_barrier();   // fragments staged

        // Phase M: wave owns k-tiles 4w..4w+3; 3 c-tiles; 2 p-subtiles
#pragma unroll
        for (int ps = 0; ps < 2; ++ps) {
            int4v bfr[3];
#pragma unroll
            for (int ct = 0; ct < 3; ++ct)
                bfr[ct] = *(int4v*)&lsB[((ct * 2 + ps) * 64 + lane) * 8];
#pragma unroll
            for (int ktl = 0; ktl < 4; ++ktl) {
                const int kt = wave * 4 + ktl;
                int4v af = *(int4v*)&lsA[((kt * 2 + ps) * 64 + lane) * 8];
#pragma unroll
                for (int ct = 0; ct < 3; ++ct) {
                    asm("v_mfma_f32_16x16x32_bf16 %0, %1, %2, %0"
                        : "+v"(acc[ktl][ct])
                        : "v"(af), "v"(bfr[ct]));
                }
            }
        }

        wg_barrier();   // frags consumed; next Phase Z may overwrite
    }

    // MFMA -> VALU read hazard guard before the flush reads acc
    asm volatile("s_nop 7\n\ts_nop 7");

    // flush: plain streaming stores of this block's partial (no atomics)
    float* pb = part + (size_t)(b * bpbk + blkb) * KFS;
    const int col = lane & 15;
    const int rw0 = (lane >> 4) * 4;
#pragma unroll
    for (int ktl = 0; ktl < 4; ++ktl) {
        const int kt = wave * 4 + ktl;
#pragma unroll
        for (int ct = 0; ct < 3; ++ct) {
            const int c = ct * 16 + col;
            if (c > CCH) continue;      // ct=2: only col 0 (wsum) is real
#pragma unroll
            for (int i = 0; i < 4; ++i) {
                const int k = kt * 16 + rw0 + i;
                pb[(size_t)k * FST + c] = acc[ktl][ct][i];
            }
        }
    }
}

// Stage A: parallel cross-block reduction. Block (b,g) owns 64 consecutive
// columns (132*64 == KFS). Wave w lane l sums col g*64+l over blk = w+4i:
// every wave-load is 64 consecutive floats (256B, coalesced; KFS*4 = 33792
// is 256B-aligned). 4 accumulators -> deep independent load stream.
__global__ __launch_bounds__(256) void spx_reduce_kernel(
    const float* __restrict__ part,   // [B*bpbk][KFS]
    float*       __restrict__ fsum,   // [B][KFS]
    int bpbk)
{
    __shared__ float red[4][64];

    const int gpb = KFS / 64;         // 132
    const int b   = blockIdx.x / gpb;
    const int g   = blockIdx.x - b * gpb;
    const int w   = threadIdx.x >> 6;
    const int l   = threadIdx.x & 63;

    const float* p = part + (size_t)b * bpbk * KFS + g * 64 + l;
    const int n = bpbk >> 2;          // partials per wave (>= 16, mult of 4)
    float s0 = 0.f, s1 = 0.f, s2 = 0.f, s3 = 0.f;
    for (int i = 0; i < n; i += 4) {
        s0 += p[(size_t)(w + 4 * (i + 0)) * KFS];
        s1 += p[(size_t)(w + 4 * (i + 1)) * KFS];
        s2 += p[(size_t)(w + 4 * (i + 2)) * KFS];
        s3 += p[(size_t)(w + 4 * (i + 3)) * KFS];
    }
    red[w][l] = (s0 + s1) + (s2 + s3);
    __syncthreads();

    if (threadIdx.x < 64)
        fsum[(size_t)b * KFS + g * 64 + threadIdx.x] =
            (red[0][threadIdx.x] + red[1][threadIdx.x]) +
            (red[2][threadIdx.x] + red[3][threadIdx.x]);
}

// Stage B: trivial division; fsum is 135 KB (L2-hot), out writes coalesced.
__global__ __launch_bounds__(256) void spx_divide_kernel(
    const float* __restrict__ fsum,  // [B][KFS]
    float*       __restrict__ out,   // [B][C][K]
    int K, int total)
{
    const int gid = blockIdx.x * 256 + threadIdx.x;
    if (gid >= total) return;
    const int k = gid % K;
    const int c = (gid / K) % CCH;
    const int b = gid / (K * CCH);
    const float* f = fsum + (size_t)b * KFS + (size_t)k * FST;
    const float W = f[CCH];
    out[gid] = (W > 1e-16f) ? (f[c] / W) : 0.f;
}

extern "C" void kernel_launch(void* const* d_in, const int* in_sizes, int n_in,
                              void* d_out, int out_size, void* d_ws, size_t ws_size,
                              hipStream_t stream) {
    const float* pf     = (const float*)d_in[0];
    const float* assoc  = (const float*)d_in[1];
    const int*   idxmap = (const int*)d_in[2];
    const int*   nw_p   = (const int*)d_in[3];
    const int*   nh_p   = (const int*)d_in[4];
    float* out = (float*)d_out;

    const int BP = in_sizes[2];          // B*P = 262144
    const int B  = 4;                    // fixed by reference setup
    const int P  = BP / B;               // 65536
    const int K  = out_size / (B * CCH); // 256 (== KMAX)

    // ws: part [B*bpbk][KFS] | fsum [B][KFS]
    const size_t fsum_bytes = (size_t)B * KFS * sizeof(float);
    int bpbk = 256;                      // 1024 blocks -> 4 blocks/CU
    while ((size_t)B * bpbk * KFS * sizeof(float) + fsum_bytes > ws_size
           && bpbk > 64)
        bpbk >>= 1;
    const int cpb = (P / 64) / bpbk;     // 4 (or 8/16 fallback)
    float* part = (float*)d_ws;
    float* fsum = (float*)((char*)d_ws
                           + (size_t)B * bpbk * KFS * sizeof(float));

    spx_mfma_kernel<<<B * bpbk, 256, 0, stream>>>(
        pf, assoc, idxmap, nw_p, nh_p, part, P, K, cpb, bpbk);

    spx_reduce_kernel<<<B * (KFS / 64), 256, 0, stream>>>(part, fsum, bpbk);

    const int total = B * K * CCH;
    spx_divide_kernel<<<(total + 255) / 256, 256, 0, stream>>>(
        fsum, out, K, total);
}